// Round 2
// baseline (169.731 us; speedup 1.0000x reference)
//
#include <hip/hip_runtime.h>
#include <math.h>

// Geodesic loss: mean over B of acos(clip((sum_ij m1*m2 - 1)*0.5, -1, 1)).
// HBM-bound: 151 MB read. 4 matrices = 36 floats = 9 float4 (144 B) per
// thread per input. R1 lesson: array-based unpack made LLVM serialize the
// loads (VGPR=32, 2 in flight, 1.8 TB/s, VALUBusy 3.5%). Fix: 18 *named*
// float4 registers so all loads issue before first use (~9KB/wave in
// flight), __launch_bounds__(256,2) to un-cap the register budget.

#define TPB 256
#define MPT 4   // matrices per thread

__global__ __launch_bounds__(TPB, 2) void geo_kernel(
    const float* __restrict__ a, const float* __restrict__ b,
    float* __restrict__ out, float invM, int M)
{
    const long long t  = (long long)blockIdx.x * TPB + threadIdx.x;
    const long long m0 = t * (long long)MPT;
    float sum = 0.0f;

    if (m0 + MPT <= M) {
        const float4* __restrict__ a4 = (const float4*)a + t * 9;
        const float4* __restrict__ b4 = (const float4*)b + t * 9;
        // Issue ALL 18 loads before any arithmetic -> 18 outstanding
        // global_load_dwordx4 per thread, s_waitcnt vmcnt(N) descending.
        float4 A0 = a4[0], A1 = a4[1], A2 = a4[2], A3 = a4[3], A4 = a4[4],
               A5 = a4[5], A6 = a4[6], A7 = a4[7], A8 = a4[8];
        float4 B0 = b4[0], B1 = b4[1], B2 = b4[2], B3 = b4[3], B4 = b4[4],
               B5 = b4[5], B6 = b4[6], B7 = b4[7], B8 = b4[8];

        // matrix 0 = floats [0..8]   = A0.xyzw A1.xyzw A2.x
        float c0 = A0.x * B0.x;
        c0 = fmaf(A0.y, B0.y, c0); c0 = fmaf(A0.z, B0.z, c0);
        c0 = fmaf(A0.w, B0.w, c0); c0 = fmaf(A1.x, B1.x, c0);
        c0 = fmaf(A1.y, B1.y, c0); c0 = fmaf(A1.z, B1.z, c0);
        c0 = fmaf(A1.w, B1.w, c0); c0 = fmaf(A2.x, B2.x, c0);
        // matrix 1 = floats [9..17]  = A2.yzw A3.xyzw A4.xy
        float c1 = A2.y * B2.y;
        c1 = fmaf(A2.z, B2.z, c1); c1 = fmaf(A2.w, B2.w, c1);
        c1 = fmaf(A3.x, B3.x, c1); c1 = fmaf(A3.y, B3.y, c1);
        c1 = fmaf(A3.z, B3.z, c1); c1 = fmaf(A3.w, B3.w, c1);
        c1 = fmaf(A4.x, B4.x, c1); c1 = fmaf(A4.y, B4.y, c1);
        // matrix 2 = floats [18..26] = A4.zw A5.xyzw A6.xyz
        float c2 = A4.z * B4.z;
        c2 = fmaf(A4.w, B4.w, c2); c2 = fmaf(A5.x, B5.x, c2);
        c2 = fmaf(A5.y, B5.y, c2); c2 = fmaf(A5.z, B5.z, c2);
        c2 = fmaf(A5.w, B5.w, c2); c2 = fmaf(A6.x, B6.x, c2);
        c2 = fmaf(A6.y, B6.y, c2); c2 = fmaf(A6.z, B6.z, c2);
        // matrix 3 = floats [27..35] = A6.w A7.xyzw A8.xyzw
        float c3 = A6.w * B6.w;
        c3 = fmaf(A7.x, B7.x, c3); c3 = fmaf(A7.y, B7.y, c3);
        c3 = fmaf(A7.z, B7.z, c3); c3 = fmaf(A7.w, B7.w, c3);
        c3 = fmaf(A8.x, B8.x, c3); c3 = fmaf(A8.y, B8.y, c3);
        c3 = fmaf(A8.z, B8.z, c3); c3 = fmaf(A8.w, B8.w, c3);

        c0 = fminf(1.0f, fmaxf(-1.0f, (c0 - 1.0f) * 0.5f));
        c1 = fminf(1.0f, fmaxf(-1.0f, (c1 - 1.0f) * 0.5f));
        c2 = fminf(1.0f, fmaxf(-1.0f, (c2 - 1.0f) * 0.5f));
        c3 = fminf(1.0f, fmaxf(-1.0f, (c3 - 1.0f) * 0.5f));
        sum = (acosf(c0) + acosf(c1)) + (acosf(c2) + acosf(c3));
    } else {
        // tail path (unused when M % (TPB*MPT) == 0, kept for generality)
        for (int j = 0; j < MPT; ++j) {
            long long m = m0 + j;
            if (m < M) {
                float c = 0.0f;
                for (int k = 0; k < 9; ++k)
                    c = fmaf(a[m * 9 + k], b[m * 9 + k], c);
                float cosv = fminf(1.0f, fmaxf(-1.0f, (c - 1.0f) * 0.5f));
                sum += acosf(cosv);
            }
        }
    }

    // wave reduce (64-wide) -> block reduce -> one atomicAdd per block
    #pragma unroll
    for (int off = 32; off > 0; off >>= 1)
        sum += __shfl_down(sum, off, 64);
    __shared__ float ws[TPB / 64];
    const int lane = threadIdx.x & 63;
    const int wid  = threadIdx.x >> 6;
    if (lane == 0) ws[wid] = sum;
    __syncthreads();
    if (threadIdx.x == 0) {
        float s = 0.0f;
        #pragma unroll
        for (int i = 0; i < TPB / 64; ++i) s += ws[i];
        atomicAdd(out, s * invM);   // device-scope by default on gfx950
    }
}

extern "C" void kernel_launch(void* const* d_in, const int* in_sizes, int n_in,
                              void* d_out, int out_size, void* d_ws, size_t ws_size,
                              hipStream_t stream) {
    const float* a = (const float*)d_in[0];
    const float* b = (const float*)d_in[1];
    float* out = (float*)d_out;

    const int n = in_sizes[0];   // flat float count = 9*M
    const int M = n / 9;         // number of 3x3 matrices

    const int nthreads = (M + MPT - 1) / MPT;
    const int grid     = (nthreads + TPB - 1) / TPB;   // 2048 for B=2^21

    // d_out is poisoned 0xAA before every timed launch; zero it (async,
    // graph-capture safe), then accumulate the mean with per-block atomics.
    hipMemsetAsync(out, 0, (size_t)out_size * sizeof(float), stream);
    geo_kernel<<<grid, TPB, 0, stream>>>(a, b, out, 1.0f / (float)M, M);
}